// Round 9
// baseline (396.091 us; speedup 1.0000x reference)
//
#include <hip/hip_runtime.h>
#include <math.h>

#define SRC_LEN  1024
#define BSZ      64
#define CDIM     1024
#define ADIM     1024
#define KDIM     1024
#define MROWS    (SRC_LEN * BSZ)
#define NEG_MASK -1000000.0f

// tiled fp16 layout (256-row tiles): tile = 256 rows x 64 cols,
//   fr = row>>4 (0..15), lr = row&15, ks = col>>5, g = (col>>3)&3, e = col&7
//   hw = fr*1024 + ks*512 + g*128 + lr*8 + e   (tile = 16384 hw = 32 KB)
// => fragment ds_read_b128 (64 lanes) covers 1KB contiguous -> conflict-free.
#define THW256 16384

typedef _Float16 f16x8 __attribute__((ext_vector_type(8)));
typedef _Float16 f16x4 __attribute__((ext_vector_type(4)));
typedef float    f32x4 __attribute__((ext_vector_type(4)));

__device__ __forceinline__ float fast_tanh(float x) {
    float e = __expf(2.0f * x);
    return 1.0f - 2.0f / (e + 1.0f);
}

// async global(16B) -> LDS, per-lane global src, wave-uniform LDS base
__device__ __forceinline__ void gload16(const _Float16* g, _Float16* l) {
    __builtin_amdgcn_global_load_lds(
        (const __attribute__((address_space(1))) unsigned int*)g,
        (__attribute__((address_space(3))) unsigned int*)l, 16, 0, 0);
}

__device__ __forceinline__ f16x8 frag(const _Float16* buf, int fr, int ks,
                                      int g, int lc) {
    return *reinterpret_cast<const f16x8*>(
        &buf[fr * 1024 + ks * 512 + g * 128 + lc * 8]);
}

__device__ __forceinline__ f16x8 cvt8(float4 x, float4 y) {
    f16x8 o;
    o[0] = (_Float16)x.x; o[1] = (_Float16)x.y;
    o[2] = (_Float16)x.z; o[3] = (_Float16)x.w;
    o[4] = (_Float16)y.x; o[5] = (_Float16)y.y;
    o[6] = (_Float16)y.z; o[7] = (_Float16)y.w;
    return o;
}

// ---------------------------------------------------------------------------
// fp32 [rows][1024] -> fp16 tiled, 256-row tiles (used for W_enc, 2MB only).
// ---------------------------------------------------------------------------
__global__ __launch_bounds__(256)
void convert_tiled256_kernel(const float* __restrict__ in, _Float16* __restrict__ out)
{
    const int bid  = blockIdx.x;
    const int part = bid & 7;
    const int tile = bid >> 3;           // rt*16 + kt
    const int kt   = tile & 15;
    const int rt   = tile >> 4;
    const int t    = threadIdx.x;
    const int u    = part * 256 + t;     // 8-elem group 0..2047
    // decompose against hw = fr*1024 + ks*512 + g*128 + lr*8 : u = hw/8
    const int fr = u >> 7;
    const int ks = (u >> 6) & 1;
    const int gg = (u >> 4) & 3;
    const int lr = u & 15;

    const size_t row = (size_t)rt * 256 + fr * 16 + lr;
    const int    col = kt * 64 + ks * 32 + gg * 8;

    float4 x = *reinterpret_cast<const float4*>(&in[row * KDIM + col]);
    float4 y = *reinterpret_cast<const float4*>(&in[row * KDIM + col + 4]);
    *reinterpret_cast<f16x8*>(&out[(size_t)tile * THW256 + (size_t)u * 8]) = cvt8(x, y);
}

// ---------------------------------------------------------------------------
// fp32 -> fp16 linear (fallback path W conversion)
// ---------------------------------------------------------------------------
__global__ __launch_bounds__(256)
void convert8_kernel(const float* __restrict__ in, _Float16* __restrict__ out)
{
    size_t i = ((size_t)blockIdx.x * 256 + threadIdx.x) * 8;
    float4 x = *reinterpret_cast<const float4*>(in + i);
    float4 y = *reinterpret_cast<const float4*>(in + i + 4);
    *reinterpret_cast<f16x8*>(out + i) = cvt8(x, y);
}

// ---------------------------------------------------------------------------
// decb[b][n] += decoder_state @ W_dec^T  (k-split, atomic; no bias)
// ---------------------------------------------------------------------------
__global__ __launch_bounds__(256)
void dec_kernel(const float* __restrict__ A, const float* __restrict__ W,
                float* __restrict__ out)
{
    const int n0  = blockIdx.x * 64;
    const int k0  = blockIdx.y * 256;
    const int tid = threadIdx.x;
    const int tx  = tid & 15;
    const int ty  = tid >> 4;

    __shared__ float Asl[16][64];
    __shared__ float Bsl[16][64];

    float acc[4][4];
#pragma unroll
    for (int i = 0; i < 4; ++i)
#pragma unroll
        for (int j = 0; j < 4; ++j) acc[i][j] = 0.f;

    const int lr = tid >> 2;
    const int lk = (tid & 3) * 4;

    for (int kb = k0; kb < k0 + 256; kb += 16) {
        float4 a4 = *reinterpret_cast<const float4*>(&A[(size_t)lr * KDIM + kb + lk]);
        float4 b4 = *reinterpret_cast<const float4*>(&W[(size_t)(n0 + lr) * KDIM + kb + lk]);
        __syncthreads();
        Asl[lk + 0][lr] = a4.x; Asl[lk + 1][lr] = a4.y;
        Asl[lk + 2][lr] = a4.z; Asl[lk + 3][lr] = a4.w;
        Bsl[lk + 0][lr] = b4.x; Bsl[lk + 1][lr] = b4.y;
        Bsl[lk + 2][lr] = b4.z; Bsl[lk + 3][lr] = b4.w;
        __syncthreads();
#pragma unroll
        for (int k = 0; k < 16; ++k) {
            float4 av = *reinterpret_cast<const float4*>(&Asl[k][ty * 4]);
            float4 bv = *reinterpret_cast<const float4*>(&Bsl[k][tx * 4]);
            float am[4] = {av.x, av.y, av.z, av.w};
            float bn[4] = {bv.x, bv.y, bv.z, bv.w};
#pragma unroll
            for (int i = 0; i < 4; ++i)
#pragma unroll
                for (int j = 0; j < 4; ++j)
                    acc[i][j] = fmaf(am[i], bn[j], acc[i][j]);
        }
    }
#pragma unroll
    for (int i = 0; i < 4; ++i) {
        int m = ty * 4 + i;
#pragma unroll
        for (int j = 0; j < 4; ++j) {
            int n = n0 + tx * 4 + j;
            atomicAdd(&out[(size_t)m * ADIM + n], acc[i][j]);
        }
    }
}

// ---------------------------------------------------------------------------
// FAST PATH: fused A-convert + enc-projection + tanh + v-dot.
// 256x256 tile, BK=64, 8 waves (2Mx4N), wave tile 128x64.
// A (fp32) is reg-staged: 2 batches of 4xfloat4 per thread per K-tile,
// cvt->ds_write_b128 into fragment-major LDS. B (fp16 tiled) via gload_lds.
// 4 phases per K-tile: {ds_read frags || stage work -> barrier -> lgkmcnt(0)
// -> setprio(1) -> 16 MFMA -> setprio(0) -> barrier}; vmcnt(0) only at tile
// boundary (B gloads have 2-phase slack; A reg-load waits are compiler-counted).
// ---------------------------------------------------------------------------
__global__ __launch_bounds__(512, 1)
void enc_score_fused(const float* __restrict__ A,      // [65536][1024] fp32
                     const _Float16* __restrict__ Bt,  // [4*16] tiles fp16
                     const float* __restrict__ decb,   // [64][1024] (no bias)
                     const float* __restrict__ be,     // b_enc
                     const float* __restrict__ bd,     // b_dec
                     const float* __restrict__ v,      // [1024]
                     float* __restrict__ scores)       // [65536]
{
    // nwg=1024, XCD-grouped: the 4 nbt-sharers of one mb on one XCD.
    const int bid = blockIdx.x;
    const int nbt = (bid >> 3) & 3;
    const int mb  = (bid & 7) + ((bid >> 5) << 3);
    const int m0 = mb * 256, n0 = nbt * 256;
    const int tid  = threadIdx.x;
    const int lane = tid & 63;
    const int wid  = tid >> 6;          // 0..7
    const int wm   = wid >> 2;          // 0..1
    const int wn   = wid & 3;           // 0..3
    const int lc   = lane & 15, g = lane >> 4;

    __shared__ __align__(16) _Float16 As[2][THW256];   // 64 KB
    __shared__ __align__(16) _Float16 Bs[2][THW256];   // 64 KB

    f32x4 acc[8][4];
#pragma unroll
    for (int i = 0; i < 8; ++i)
#pragma unroll
        for (int j = 0; j < 4; ++j) acc[i][j] = (f32x4){0.f, 0.f, 0.f, 0.f};

    // --- A staging coords: thread -> (row sr, k-half sks), 32 fp32 each ---
    const int sr  = tid >> 1;            // 0..255
    const int sks = tid & 1;             // 0,1
    const int whw = (sr >> 4) * 1024 + sks * 512 + (sr & 15) * 8;  // + g2*128
    const float* Arow = A + (size_t)(m0 + sr) * KDIM + sks * 32;

    const _Float16* Bbase = Bt + (size_t)(nbt * 16) * THW256;

    float4 aR[8];

    // ---- prologue: stage K-tile 0 ----
    {
        const float4* Ap = reinterpret_cast<const float4*>(Arow);
#pragma unroll
        for (int i = 0; i < 8; ++i) aR[i] = Ap[i];
#pragma unroll
        for (int i = 0; i < 4; ++i) {
            int c = wid * 4 + i;                    // chunk 0..31 (1KB)
            gload16(Bbase + c * 512 + lane * 8, &Bs[0][c * 512]);
        }
#pragma unroll
        for (int g2 = 0; g2 < 4; ++g2)
            *reinterpret_cast<f16x8*>(&As[0][whw + g2 * 128]) =
                cvt8(aR[2 * g2], aR[2 * g2 + 1]);
        asm volatile("s_waitcnt vmcnt(0)" ::: "memory");
        asm volatile("s_waitcnt lgkmcnt(0)" ::: "memory");
        __builtin_amdgcn_s_barrier();
        asm volatile("" ::: "memory");
    }

    for (int kt = 0; kt < 16; ++kt) {
        const int cur = kt & 1;
        const _Float16* Acur = As[cur];
        const _Float16* Bcur = Bs[cur];
        _Float16* Anxt = As[cur ^ 1];
        _Float16* Bnxt = Bs[cur ^ 1];
        const bool pre = (kt < 15);
        const float4* Ap = reinterpret_cast<const float4*>(Arow + (kt + 1) * 64);
        const _Float16* Bg = Bbase + (size_t)(kt + 1) * THW256;

        f16x8 af[4], bf[4];

        // ===== phase 0: ks=0, mi 0..3  (+ issue A batch0 of kt+1) =====
#pragma unroll
        for (int ni = 0; ni < 4; ++ni) bf[ni] = frag(Bcur, wn * 4 + ni, 0, g, lc);
#pragma unroll
        for (int i = 0; i < 4; ++i)    af[i]  = frag(Acur, wm * 8 + i, 0, g, lc);
        if (pre) {
#pragma unroll
            for (int i = 0; i < 4; ++i) aR[i] = Ap[i];
        }
        __builtin_amdgcn_s_barrier();
        asm volatile("s_waitcnt lgkmcnt(0)" ::: "memory");
        __builtin_amdgcn_sched_barrier(0);
        __builtin_amdgcn_s_setprio(1);
#pragma unroll
        for (int i = 0; i < 4; ++i)
#pragma unroll
            for (int ni = 0; ni < 4; ++ni)
                acc[i][ni] = __builtin_amdgcn_mfma_f32_16x16x32_f16(
                    af[i], bf[ni], acc[i][ni], 0, 0, 0);
        __builtin_amdgcn_s_setprio(0);
        __builtin_amdgcn_s_barrier();

        // ===== phase 1: ks=0, mi 4..7 =====
        // (+ write A batch0, issue A batch1, issue B gloads for kt+1)
#pragma unroll
        for (int i = 0; i < 4; ++i) af[i] = frag(Acur, wm * 8 + 4 + i, 0, g, lc);
        if (pre) {
            // cvt waits batch0 (compiler-counted vmcnt; batch1/B not yet issued)
            *reinterpret_cast<f16x8*>(&Anxt[whw + 0 * 128]) = cvt8(aR[0], aR[1]);
            *reinterpret_cast<f16x8*>(&Anxt[whw + 1 * 128]) = cvt8(aR[2], aR[3]);
#pragma unroll
            for (int i = 0; i < 4; ++i) aR[4 + i] = Ap[4 + i];
#pragma unroll
            for (int i = 0; i < 4; ++i) {
                int c = wid * 4 + i;
                gload16(Bg + c * 512 + lane * 8, Bnxt + c * 512);
            }
        }
        __builtin_amdgcn_s_barrier();
        asm volatile("s_waitcnt lgkmcnt(0)" ::: "memory");
        __builtin_amdgcn_sched_barrier(0);
        __builtin_amdgcn_s_setprio(1);
#pragma unroll
        for (int i = 0; i < 4; ++i)
#pragma unroll
            for (int ni = 0; ni < 4; ++ni)
                acc[4 + i][ni] = __builtin_amdgcn_mfma_f32_16x16x32_f16(
                    af[i], bf[ni], acc[4 + i][ni], 0, 0, 0);
        __builtin_amdgcn_s_setprio(0);
        __builtin_amdgcn_s_barrier();

        // ===== phase 2: ks=1, mi 0..3  (+ write A batch1) =====
#pragma unroll
        for (int ni = 0; ni < 4; ++ni) bf[ni] = frag(Bcur, wn * 4 + ni, 1, g, lc);
#pragma unroll
        for (int i = 0; i < 4; ++i)    af[i]  = frag(Acur, wm * 8 + i, 1, g, lc);
        if (pre) {
            // cvt waits batch1 (vmcnt(4): B gloads newer, stay in flight)
            *reinterpret_cast<f16x8*>(&Anxt[whw + 2 * 128]) = cvt8(aR[4], aR[5]);
            *reinterpret_cast<f16x8*>(&Anxt[whw + 3 * 128]) = cvt8(aR[6], aR[7]);
        }
        __builtin_amdgcn_s_barrier();
        asm volatile("s_waitcnt lgkmcnt(0)" ::: "memory");
        __builtin_amdgcn_sched_barrier(0);
        __builtin_amdgcn_s_setprio(1);
#pragma unroll
        for (int i = 0; i < 4; ++i)
#pragma unroll
            for (int ni = 0; ni < 4; ++ni)
                acc[i][ni] = __builtin_amdgcn_mfma_f32_16x16x32_f16(
                    af[i], bf[ni], acc[i][ni], 0, 0, 0);
        __builtin_amdgcn_s_setprio(0);
        __builtin_amdgcn_s_barrier();

        // ===== phase 3: ks=1, mi 4..7  (+ drain B gloads) =====
#pragma unroll
        for (int i = 0; i < 4; ++i) af[i] = frag(Acur, wm * 8 + 4 + i, 1, g, lc);
        __builtin_amdgcn_s_barrier();
        asm volatile("s_waitcnt lgkmcnt(0)" ::: "memory");
        __builtin_amdgcn_sched_barrier(0);
        __builtin_amdgcn_s_setprio(1);
#pragma unroll
        for (int i = 0; i < 4; ++i)
#pragma unroll
            for (int ni = 0; ni < 4; ++ni)
                acc[4 + i][ni] = __builtin_amdgcn_mfma_f32_16x16x32_f16(
                    af[i], bf[ni], acc[4 + i][ni], 0, 0, 0);
        __builtin_amdgcn_s_setprio(0);
        if (pre) asm volatile("s_waitcnt vmcnt(0)" ::: "memory");
        __builtin_amdgcn_s_barrier();
        asm volatile("" ::: "memory");
    }

    // ---- fused epilogue: tanh + v-dot + reduce ----
    __syncthreads();

    float psum[8][4];
#pragma unroll
    for (int mi = 0; mi < 8; ++mi)
#pragma unroll
        for (int r = 0; r < 4; ++r) psum[mi][r] = 0.f;

#pragma unroll
    for (int mi = 0; mi < 8; ++mi) {
#pragma unroll
        for (int ni = 0; ni < 4; ++ni) {
            int n = n0 + wn * 64 + ni * 16 + lc;
            float vn = v[n];
            float bb = be[n] + bd[n];
#pragma unroll
            for (int r = 0; r < 4; ++r) {
                int b = ((mi & 3) * 16) + g * 4 + r;   // row & 63
                float x = acc[mi][ni][r] + decb[(size_t)b * ADIM + n] + bb;
                psum[mi][r] = fmaf(fast_tanh(x), vn, psum[mi][r]);
            }
        }
    }
#pragma unroll
    for (int mi = 0; mi < 8; ++mi)
#pragma unroll
        for (int r = 0; r < 4; ++r) {
            float s = psum[mi][r];
            s += __shfl_xor(s, 1);
            s += __shfl_xor(s, 2);
            s += __shfl_xor(s, 4);
            s += __shfl_xor(s, 8);
            psum[mi][r] = s;
        }

    float* red = reinterpret_cast<float*>(&As[0][0]);   // [256][4]
    if (lc == 0) {
#pragma unroll
        for (int mi = 0; mi < 8; ++mi)
#pragma unroll
            for (int r = 0; r < 4; ++r) {
                int row = wm * 128 + mi * 16 + g * 4 + r;
                red[row * 4 + wn] = psum[mi][r];
            }
    }
    __syncthreads();
    if (tid < 256)
        atomicAdd(&scores[m0 + tid],
                  red[tid * 4] + red[tid * 4 + 1] + red[tid * 4 + 2] + red[tid * 4 + 3]);
}

// ---------------------------------------------------------------------------
// FALLBACK (ws too small): reg-staged fp32-A 128x128 version.
// ---------------------------------------------------------------------------
__global__ __launch_bounds__(256)
void enc_score_fallback(const float* __restrict__ A,
                        const _Float16* __restrict__ Bw,
                        const float* __restrict__ decb,
                        const float* __restrict__ be,
                        const float* __restrict__ bd,
                        const float* __restrict__ v,
                        float* __restrict__ scores)
{
    const int bid = blockIdx.x;
    const int nb  = (bid >> 3) & 7;
    const int mb  = (bid & 7) + ((bid >> 6) << 3);
    const int m0 = mb * 128, n0 = nb * 128;
    const int tid  = threadIdx.x;
    const int lane = tid & 63;
    const int wid  = tid >> 6;
    const int wm   = wid >> 1, wn = wid & 1;
    const int lc   = lane & 15, g = lane >> 4;

    __shared__ __align__(16) _Float16 As[128 * 64];
    __shared__ __align__(16) _Float16 Bs[128 * 64];

    const int srow = tid >> 1;
    const int scol = (tid & 1) * 32;
    const int sw   = (srow & 7) << 3;

    f32x4 acc[4][4];
#pragma unroll
    for (int i = 0; i < 4; ++i)
#pragma unroll
        for (int j = 0; j < 4; ++j) acc[i][j] = (f32x4){0.f, 0.f, 0.f, 0.f};

    const float*    Aptr = A  + (size_t)(m0 + srow) * KDIM + scol;
    const _Float16* Bptr = Bw + (size_t)(n0 + srow) * KDIM + scol;

    float4 aR[8];
    uint4  bR[4];
#pragma unroll
    for (int i = 0; i < 8; ++i) aR[i] = reinterpret_cast<const float4*>(Aptr)[i];
#pragma unroll
    for (int i = 0; i < 4; ++i) bR[i] = reinterpret_cast<const uint4*>(Bptr)[i];

    for (int kb = 0; kb < KDIM; kb += 64) {
        __syncthreads();
#pragma unroll
        for (int w = 0; w < 4; ++w) {
            float4 x = aR[2 * w], y = aR[2 * w + 1];
            int hw = (srow * 64 + scol + 8 * w) ^ sw;
            *reinterpret_cast<f16x8*>(&As[hw]) = cvt8(x, y);
            *reinterpret_cast<uint4*>(&Bs[hw]) = bR[w];
        }
        __syncthreads();
        if (kb + 64 < KDIM) {
#pragma unroll
            for (int i = 0; i < 8; ++i)
                aR[i] = reinterpret_cast<const float4*>(Aptr + kb + 64)[i];
#pragma unroll
            for (int i = 0; i < 4; ++i)
                bR[i] = reinterpret_cast<const uint4*>(Bptr + kb + 64)[i];
        }
#pragma unroll
        for (int ks = 0; ks < 2; ++ks) {
            f16x8 af[4], bf[4];
#pragma unroll
            for (int mi = 0; mi < 4; ++mi) {
                int r  = wm * 64 + mi * 16 + lc;
                int hw = (r * 64 + ks * 32 + g * 8) ^ ((r & 7) << 3);
                af[mi] = *reinterpret_cast<const f16x8*>(&As[hw]);
            }
#pragma unroll
            for (int ni = 0; ni < 4; ++ni) {
                int r  = wn * 64 + ni * 16 + lc;
                int hw = (r * 64 + ks * 32 + g * 8) ^ ((r & 7) << 3);
                bf[ni] = *reinterpret_cast<const f16x8*>(&Bs[hw]);
            }
#pragma unroll
            for (int mi = 0; mi < 4; ++mi)
#pragma unroll
                for (int ni = 0; ni < 4; ++ni)
                    acc[mi][ni] = __builtin_amdgcn_mfma_f32_16x16x32_f16(
                        af[mi], bf[ni], acc[mi][ni], 0, 0, 0);
        }
    }

    __syncthreads();

    float psum[4][4];
#pragma unroll
    for (int mi = 0; mi < 4; ++mi)
#pragma unroll
        for (int r = 0; r < 4; ++r) psum[mi][r] = 0.f;

#pragma unroll
    for (int mi = 0; mi < 4; ++mi) {
#pragma unroll
        for (int ni = 0; ni < 4; ++ni) {
            int n = n0 + wn * 64 + ni * 16 + lc;
            float vn = v[n];
            float bb = be[n] + bd[n];
#pragma unroll
            for (int r = 0; r < 4; ++r) {
                int b = mi * 16 + g * 4 + r;
                float x = acc[mi][ni][r] + decb[(size_t)b * ADIM + n] + bb;
                psum[mi][r] = fmaf(fast_tanh(x), vn, psum[mi][r]);
            }
        }
    }
#pragma unroll
    for (int mi = 0; mi < 4; ++mi)
#pragma unroll
        for (int r = 0; r < 4; ++r) {
            float s = psum[mi][r];
            s += __shfl_xor(s, 1);
            s += __shfl_xor(s, 2);
            s += __shfl_xor(s, 4);
            s += __shfl_xor(s, 8);
            psum[mi][r] = s;
        }

    float* red = reinterpret_cast<float*>(As);
    if (lc == 0) {
#pragma unroll
        for (int mi = 0; mi < 4; ++mi)
#pragma unroll
            for (int r = 0; r < 4; ++r) {
                int row = wm * 64 + mi * 16 + g * 4 + r;
                red[row * 2 + wn] = psum[mi][r];
            }
    }
    __syncthreads();
    if (tid < 128)
        atomicAdd(&scores[m0 + tid], red[tid * 2] + red[tid * 2 + 1]);
}

// ---------------------------------------------------------------------------
// Masked softmax over S per batch column, in place. One block per b.
// ---------------------------------------------------------------------------
__global__ __launch_bounds__(256)
void softmax_kernel(const int* __restrict__ lens, float* __restrict__ attn)
{
    const int b   = blockIdx.x;
    const int tid = threadIdx.x;
    const int len = lens[b];

    float sc[4];
#pragma unroll
    for (int k = 0; k < 4; ++k) {
        int s = k * 256 + tid;
        float x = attn[(size_t)s * BSZ + b];
        sc[k] = (s < len) ? x : NEG_MASK;
    }

    __shared__ float red[8];

    float m = fmaxf(fmaxf(sc[0], sc[1]), fmaxf(sc[2], sc[3]));
#pragma unroll
    for (int off = 32; off > 0; off >>= 1) m = fmaxf(m, __shfl_xor(m, off));
    if ((tid & 63) == 0) red[tid >> 6] = m;
    __syncthreads();
    m = fmaxf(fmaxf(red[0], red[1]), fmaxf(red[2], red[3]));

    float e[4];
    float sum = 0.f;
#pragma unroll
    for (int k = 0; k < 4; ++k) { e[k] = expf(sc[k] - m); sum += e[k]; }
#pragma unroll
    for (int off = 32; off > 0; off >>= 1) sum += __shfl_xor(sum, off);
    __syncthreads();
    if ((tid & 63) == 0) red[4 + (tid >> 6)] = sum;
    __syncthreads();
    float total = red[4] + red[5] + red[6] + red[7];
    float inv = 1.f / total;

#pragma unroll
    for (int k = 0; k < 4; ++k) {
        int s = k * 256 + tid;
        attn[(size_t)s * BSZ + b] = e[k] * inv;
    }
}

// ---------------------------------------------------------------------------
// ctx[b][c] = sum_s attn[s][b] * hids[s][b][c]   (fp32 source, coalesced)
// ---------------------------------------------------------------------------
__global__ __launch_bounds__(256)
void ctx_kernel(const float* __restrict__ hids, const float* __restrict__ attn,
                float* __restrict__ ctx)
{
    const int b   = blockIdx.x;
    const int s0  = blockIdx.y * (SRC_LEN / 8);
    const int tid = threadIdx.x;

    float4 acc = make_float4(0.f, 0.f, 0.f, 0.f);
    for (int s = s0; s < s0 + SRC_LEN / 8; ++s) {
        float w = attn[(size_t)s * BSZ + b];
        if (w != 0.f) {
            float4 h = *reinterpret_cast<const float4*>(
                &hids[((size_t)s * BSZ + b) * CDIM + tid * 4]);
            acc.x = fmaf(w, h.x, acc.x);
            acc.y = fmaf(w, h.y, acc.y);
            acc.z = fmaf(w, h.z, acc.z);
            acc.w = fmaf(w, h.w, acc.w);
        }
    }
    float* dst = &ctx[(size_t)b * CDIM + tid * 4];
    atomicAdd(dst + 0, acc.x);
    atomicAdd(dst + 1, acc.y);
    atomicAdd(dst + 2, acc.z);
    atomicAdd(dst + 3, acc.w);
}

// ---------------------------------------------------------------------------
extern "C" void kernel_launch(void* const* d_in, const int* in_sizes, int n_in,
                              void* d_out, int out_size, void* d_ws, size_t ws_size,
                              hipStream_t stream)
{
    const float* dsr   = (const float*)d_in[0];
    const float* hids  = (const float*)d_in[1];
    const int*   lens  = (const int*)  d_in[2];
    const float* W_enc = (const float*)d_in[3];
    const float* b_enc = (const float*)d_in[4];
    const float* W_dec = (const float*)d_in[5];
    const float* b_dec = (const float*)d_in[6];
    const float* v     = (const float*)d_in[7];

    float* out  = (float*)d_out;
    float* ctx  = out;                       // [64*1024]
    float* attn = out + BSZ * CDIM;          // [1024*64] scores -> probs

    const size_t decb_b = (size_t)BSZ * ADIM * 4;     // 256 KB
    const size_t wf16_b = (size_t)ADIM * KDIM * 2;    // 2 MB

    float*    decb = (float*)d_ws;
    _Float16* Wt   = (_Float16*)((char*)d_ws + decb_b);

    const bool fast = ws_size >= decb_b + wf16_b;

    hipMemsetAsync(d_out, 0, (size_t)(BSZ * CDIM + SRC_LEN * BSZ) * sizeof(float), stream);
    hipMemsetAsync(d_ws, 0, decb_b, stream);   // decb is an atomic target

    dec_kernel<<<dim3(16, 4), 256, 0, stream>>>(dsr, W_dec, decb);

    if (fast) {
        convert_tiled256_kernel<<<(ADIM / 256) * 16 * 8, 256, 0, stream>>>(W_enc, Wt);
        enc_score_fused<<<1024, 512, 0, stream>>>(hids, Wt, decb, b_enc, b_dec, v, attn);
    } else {
        convert8_kernel<<<ADIM * KDIM / 8 / 256, 256, 0, stream>>>(W_enc, Wt);
        enc_score_fallback<<<4096, 256, 0, stream>>>(hids, Wt, decb, b_enc, b_dec, v, attn);
    }
    softmax_kernel<<<BSZ, 256, 0, stream>>>(lens, attn);
    ctx_kernel<<<dim3(BSZ, 8), 256, 0, stream>>>(hids, attn, ctx);
}

// Round 11
// 355.657 us; speedup vs baseline: 1.1137x; 1.1137x over previous
//
#include <hip/hip_runtime.h>
#include <math.h>

#define SRC_LEN  1024
#define BSZ      64
#define CDIM     1024
#define ADIM     1024
#define KDIM     1024
#define MROWS    (SRC_LEN * BSZ)
#define NEG_MASK -1000000.0f

// tiled fp16 layout (256-row tiles): tile = 256 rows x 64 cols,
//   fr = row>>4 (0..15), lr = row&15, ks = col>>5, g = (col>>3)&3, e = col&7
//   hw = fr*1024 + ks*512 + g*128 + lr*8 + e   (tile = 16384 hw = 32 KB)
// Halves split at fr=8: half h = hw range [h*8192, h*8192+8192).
// => fragment ds_read_b128 (64 lanes) covers 1KB contiguous -> conflict-free,
//    staging is a plain contiguous copy.
#define THW256 16384

typedef _Float16 f16x8 __attribute__((ext_vector_type(8)));
typedef float    f32x4 __attribute__((ext_vector_type(4)));

__device__ __forceinline__ float fast_tanh(float x) {
    float e = __expf(2.0f * x);
    return 1.0f - 2.0f / (e + 1.0f);
}

// async global(16B) -> LDS, per-lane global src, wave-uniform LDS base
__device__ __forceinline__ void gload16(const _Float16* g, _Float16* l) {
    __builtin_amdgcn_global_load_lds(
        (const __attribute__((address_space(1))) unsigned int*)g,
        (__attribute__((address_space(3))) unsigned int*)l, 16, 0, 0);
}

__device__ __forceinline__ f16x8 cvt8(float4 x, float4 y) {
    f16x8 o;
    o[0] = (_Float16)x.x; o[1] = (_Float16)x.y;
    o[2] = (_Float16)x.z; o[3] = (_Float16)x.w;
    o[4] = (_Float16)y.x; o[5] = (_Float16)y.y;
    o[6] = (_Float16)y.z; o[7] = (_Float16)y.w;
    return o;
}

// ---------------------------------------------------------------------------
// fp32 [rows][1024] -> fp16 tiled, 256-row tiles (tiles: rt*16 + kt).
// ---------------------------------------------------------------------------
__global__ __launch_bounds__(256)
void convert_tiled256_kernel(const float* __restrict__ in, _Float16* __restrict__ out)
{
    const int bid  = blockIdx.x;
    const int part = bid & 7;
    const int tile = bid >> 3;           // rt*16 + kt
    const int kt   = tile & 15;
    const int rt   = tile >> 4;
    const int t    = threadIdx.x;
    const int u    = part * 256 + t;     // 8-elem group 0..2047
    const int fr = u >> 7;
    const int ks = (u >> 6) & 1;
    const int gg = (u >> 4) & 3;
    const int lr = u & 15;

    const size_t row = (size_t)rt * 256 + fr * 16 + lr;
    const int    col = kt * 64 + ks * 32 + gg * 8;

    float4 x = *reinterpret_cast<const float4*>(&in[row * KDIM + col]);
    float4 y = *reinterpret_cast<const float4*>(&in[row * KDIM + col + 4]);
    *reinterpret_cast<f16x8*>(&out[(size_t)tile * THW256 + (size_t)u * 8]) = cvt8(x, y);
}

// ---------------------------------------------------------------------------
// fp32 -> fp16 linear (fallback path W conversion)
// ---------------------------------------------------------------------------
__global__ __launch_bounds__(256)
void convert8_kernel(const float* __restrict__ in, _Float16* __restrict__ out)
{
    size_t i = ((size_t)blockIdx.x * 256 + threadIdx.x) * 8;
    float4 x = *reinterpret_cast<const float4*>(in + i);
    float4 y = *reinterpret_cast<const float4*>(in + i + 4);
    *reinterpret_cast<f16x8*>(out + i) = cvt8(x, y);
}

// ---------------------------------------------------------------------------
// decb[b][n] += decoder_state @ W_dec^T  (k-split, atomic; no bias)
// ---------------------------------------------------------------------------
__global__ __launch_bounds__(256)
void dec_kernel(const float* __restrict__ A, const float* __restrict__ W,
                float* __restrict__ out)
{
    const int n0  = blockIdx.x * 64;
    const int k0  = blockIdx.y * 256;
    const int tid = threadIdx.x;
    const int tx  = tid & 15;
    const int ty  = tid >> 4;

    __shared__ float Asl[16][64];
    __shared__ float Bsl[16][64];

    float acc[4][4];
#pragma unroll
    for (int i = 0; i < 4; ++i)
#pragma unroll
        for (int j = 0; j < 4; ++j) acc[i][j] = 0.f;

    const int lr = tid >> 2;
    const int lk = (tid & 3) * 4;

    for (int kb = k0; kb < k0 + 256; kb += 16) {
        float4 a4 = *reinterpret_cast<const float4*>(&A[(size_t)lr * KDIM + kb + lk]);
        float4 b4 = *reinterpret_cast<const float4*>(&W[(size_t)(n0 + lr) * KDIM + kb + lk]);
        __syncthreads();
        Asl[lk + 0][lr] = a4.x; Asl[lk + 1][lr] = a4.y;
        Asl[lk + 2][lr] = a4.z; Asl[lk + 3][lr] = a4.w;
        Bsl[lk + 0][lr] = b4.x; Bsl[lk + 1][lr] = b4.y;
        Bsl[lk + 2][lr] = b4.z; Bsl[lk + 3][lr] = b4.w;
        __syncthreads();
#pragma unroll
        for (int k = 0; k < 16; ++k) {
            float4 av = *reinterpret_cast<const float4*>(&Asl[k][ty * 4]);
            float4 bv = *reinterpret_cast<const float4*>(&Bsl[k][tx * 4]);
            float am[4] = {av.x, av.y, av.z, av.w};
            float bn[4] = {bv.x, bv.y, bv.z, bv.w};
#pragma unroll
            for (int i = 0; i < 4; ++i)
#pragma unroll
                for (int j = 0; j < 4; ++j)
                    acc[i][j] = fmaf(am[i], bn[j], acc[i][j]);
        }
    }
#pragma unroll
    for (int i = 0; i < 4; ++i) {
        int m = ty * 4 + i;
#pragma unroll
        for (int j = 0; j < 4; ++j) {
            int n = n0 + tx * 4 + j;
            atomicAdd(&out[(size_t)m * ADIM + n], acc[i][j]);
        }
    }
}

// ---------------------------------------------------------------------------
// FAST PATH: 256x256 tile, BK=64, 8 waves.
// Quadrant schedule with counted vmcnt: each K-tile = 4 phases; phase q
// computes C-quadrant (HA,HB) in {(0,0),(1,0),(1,1),(0,1)} (16 MFMA/wave)
// and stages ONE half-tile of kt+1 (order A0,B0,A1,B1; 2 gload16/thread).
// Phase entry: vmcnt(4) (retires exactly the half needed, >=3-phase slack)
// + one barrier. Loads stay in flight across barriers (T4).
// ---------------------------------------------------------------------------
__global__ __launch_bounds__(512, 1)
void enc_score_256(const _Float16* __restrict__ At,   // [256*16] tiles
                   const _Float16* __restrict__ Bt,   // [4*16] tiles
                   const float* __restrict__ decb,    // [64][1024] (no bias)
                   const float* __restrict__ be,      // b_enc
                   const float* __restrict__ bd,      // b_dec
                   const float* __restrict__ v,       // [1024]
                   float* __restrict__ scores)        // [65536]
{
    // nwg=1024, XCD-grouped: the 4 nbt-sharers of one mb on one XCD.
    const int bid = blockIdx.x;
    const int nbt = (bid >> 3) & 3;
    const int mb  = (bid & 7) + ((bid >> 5) << 3);
    const int m0 = mb * 256, n0 = nbt * 256;
    const int tid  = threadIdx.x;
    const int lane = tid & 63;
    const int wid  = tid >> 6;          // 0..7
    const int wm   = wid >> 2;          // 0..1
    const int wn   = wid & 3;           // 0..3
    const int lc   = lane & 15, g = lane >> 4;

    __shared__ __align__(16) _Float16 As[2][THW256];   // 64 KB
    __shared__ __align__(16) _Float16 Bs[2][THW256];   // 64 KB

    f32x4 acc[8][4];   // [HA*4+mi][HB*2+ni]
#pragma unroll
    for (int i = 0; i < 8; ++i)
#pragma unroll
        for (int j = 0; j < 4; ++j) acc[i][j] = (f32x4){0.f, 0.f, 0.f, 0.f};

    const _Float16* Abase = At + (size_t)(mb * 16) * THW256;
    const _Float16* Bbase = Bt + (size_t)(nbt * 16) * THW256;

    const int c0  = wid * 2;                 // this wave's 2 chunks per half
    const int off0 = c0 * 512 + lane * 8;
    const int off1 = (c0 + 1) * 512 + lane * 8;

    // ---- prologue: stage tile 0's 4 halves, order A0,B0,A1,B1 ----
    gload16(Abase + off0, &As[0][off0]);
    gload16(Abase + off1, &As[0][off1]);
    gload16(Bbase + off0, &Bs[0][off0]);
    gload16(Bbase + off1, &Bs[0][off1]);
    gload16(Abase + 8192 + off0, &As[0][8192 + off0]);
    gload16(Abase + 8192 + off1, &As[0][8192 + off1]);
    gload16(Bbase + 8192 + off0, &Bs[0][8192 + off0]);
    gload16(Bbase + 8192 + off1, &Bs[0][8192 + off1]);

#define PHASE(HA, HB, SBUF, SGL, SH)                                           \
    {                                                                          \
        if (kt < 15) { asm volatile("s_waitcnt vmcnt(4)" ::: "memory"); }      \
        else         { asm volatile("s_waitcnt vmcnt(0)" ::: "memory"); }      \
        __builtin_amdgcn_s_barrier();                                          \
        f16x8 af[4][2], bf[2][2];                                              \
        _Pragma("unroll")                                                      \
        for (int ks = 0; ks < 2; ++ks) {                                       \
            _Pragma("unroll")                                                  \
            for (int mi = 0; mi < 4; ++mi)                                     \
                af[mi][ks] = *reinterpret_cast<const f16x8*>(                  \
                    &As[cur][(HA)*8192 + (wm*4+mi)*1024 + ks*512 + g*128 + lc*8]); \
            _Pragma("unroll")                                                  \
            for (int ni = 0; ni < 2; ++ni)                                     \
                bf[ni][ks] = *reinterpret_cast<const f16x8*>(                  \
                    &Bs[cur][(HB)*8192 + (wn*2+ni)*1024 + ks*512 + g*128 + lc*8]); \
        }                                                                      \
        if (kt < 15) {                                                         \
            const _Float16* gsrc = (SGL) + (size_t)(kt+1)*THW256 + (SH)*8192;  \
            _Float16* ldst = &(SBUF)[cur ^ 1][(SH)*8192];                      \
            gload16(gsrc + off0, ldst + off0);                                 \
            gload16(gsrc + off1, ldst + off1);                                 \
        }                                                                      \
        asm volatile("s_waitcnt lgkmcnt(0)" ::: "memory");                     \
        __builtin_amdgcn_sched_barrier(0);                                     \
        __builtin_amdgcn_s_setprio(1);                                         \
        _Pragma("unroll")                                                      \
        for (int ks = 0; ks < 2; ++ks)                                         \
            { _Pragma("unroll")                                                \
              for (int mi = 0; mi < 4; ++mi)                                   \
                { _Pragma("unroll")                                            \
                  for (int ni = 0; ni < 2; ++ni)                               \
                    acc[(HA)*4+mi][(HB)*2+ni] =                                \
                        __builtin_amdgcn_mfma_f32_16x16x32_f16(                \
                            af[mi][ks], bf[ni][ks], acc[(HA)*4+mi][(HB)*2+ni], \
                            0, 0, 0); } }                                      \
        __builtin_amdgcn_s_setprio(0);                                         \
    }

    for (int kt = 0; kt < 16; ++kt) {
        const int cur = kt & 1;
        PHASE(0, 0, As, Abase, 0)   // q0: quad (A0,B0), stage A0(kt+1)
        PHASE(1, 0, Bs, Bbase, 0)   // q1: quad (A1,B0), stage B0(kt+1)
        PHASE(1, 1, As, Abase, 1)   // q2: quad (A1,B1), stage A1(kt+1)
        PHASE(0, 1, Bs, Bbase, 1)   // q3: quad (A0,B1), stage B1(kt+1)
    }
#undef PHASE

    // ---- fused epilogue: tanh + v-dot + reduce ----
    __syncthreads();

    float psum[8][4];  // [am][rr]
#pragma unroll
    for (int am = 0; am < 8; ++am)
#pragma unroll
        for (int r = 0; r < 4; ++r) psum[am][r] = 0.f;

#pragma unroll
    for (int am = 0; am < 8; ++am) {
#pragma unroll
        for (int an = 0; an < 4; ++an) {
            int n = n0 + (an >> 1) * 128 + wn * 32 + (an & 1) * 16 + lc;
            float vn = v[n];
            float bb = be[n] + bd[n];
#pragma unroll
            for (int r = 0; r < 4; ++r) {
                int b = (am & 3) * 16 + g * 4 + r;   // row & 63
                float x = acc[am][an][r] + decb[(size_t)b * ADIM + n] + bb;
                psum[am][r] = fmaf(fast_tanh(x), vn, psum[am][r]);
            }
        }
    }
#pragma unroll
    for (int am = 0; am < 8; ++am)
#pragma unroll
        for (int r = 0; r < 4; ++r) {
            float s = psum[am][r];
            s += __shfl_xor(s, 1);
            s += __shfl_xor(s, 2);
            s += __shfl_xor(s, 4);
            s += __shfl_xor(s, 8);
            psum[am][r] = s;
        }

    float* red = reinterpret_cast<float*>(&As[0][0]);   // [256][4]
    if (lc == 0) {
#pragma unroll
        for (int am = 0; am < 8; ++am)
#pragma unroll
            for (int r = 0; r < 4; ++r) {
                int row = (am >> 2) * 128 + wm * 64 + (am & 3) * 16 + g * 4 + r;
                red[row * 4 + wn] = psum[am][r];
            }
    }
    __syncthreads();
    if (tid < 256)
        atomicAdd(&scores[m0 + tid],
                  red[tid * 4] + red[tid * 4 + 1] + red[tid * 4 + 2] + red[tid * 4 + 3]);
}

// ---------------------------------------------------------------------------
// FALLBACK (ws too small): reg-staged fp32-A 128x128 version.
// ---------------------------------------------------------------------------
__global__ __launch_bounds__(256)
void enc_score_fallback(const float* __restrict__ A,
                        const _Float16* __restrict__ Bw,
                        const float* __restrict__ decb,
                        const float* __restrict__ be,
                        const float* __restrict__ bd,
                        const float* __restrict__ v,
                        float* __restrict__ scores)
{
    const int bid = blockIdx.x;
    const int nb  = (bid >> 3) & 7;
    const int mb  = (bid & 7) + ((bid >> 6) << 3);
    const int m0 = mb * 128, n0 = nb * 128;
    const int tid  = threadIdx.x;
    const int lane = tid & 63;
    const int wid  = tid >> 6;
    const int wm   = wid >> 1, wn = wid & 1;
    const int lc   = lane & 15, g = lane >> 4;

    __shared__ __align__(16) _Float16 As[128 * 64];
    __shared__ __align__(16) _Float16 Bs[128 * 64];

    const int srow = tid >> 1;
    const int scol = (tid & 1) * 32;
    const int sw   = (srow & 7) << 3;

    f32x4 acc[4][4];
#pragma unroll
    for (int i = 0; i < 4; ++i)
#pragma unroll
        for (int j = 0; j < 4; ++j) acc[i][j] = (f32x4){0.f, 0.f, 0.f, 0.f};

    const float*    Aptr = A  + (size_t)(m0 + srow) * KDIM + scol;
    const _Float16* Bptr = Bw + (size_t)(n0 + srow) * KDIM + scol;

    float4 aR[8];
    uint4  bR[4];
#pragma unroll
    for (int i = 0; i < 8; ++i) aR[i] = reinterpret_cast<const float4*>(Aptr)[i];
#pragma unroll
    for (int i = 0; i < 4; ++i) bR[i] = reinterpret_cast<const uint4*>(Bptr)[i];

    for (int kb = 0; kb < KDIM; kb += 64) {
        __syncthreads();
#pragma unroll
        for (int w = 0; w < 4; ++w) {
            int hw = (srow * 64 + scol + 8 * w) ^ sw;
            *reinterpret_cast<f16x8*>(&As[hw]) = cvt8(aR[2 * w], aR[2 * w + 1]);
            *reinterpret_cast<uint4*>(&Bs[hw]) = bR[w];
        }
        __syncthreads();
        if (kb + 64 < KDIM) {
#pragma unroll
            for (int i = 0; i < 8; ++i)
                aR[i] = reinterpret_cast<const float4*>(Aptr + kb + 64)[i];
#pragma unroll
            for (int i = 0; i < 4; ++i)
                bR[i] = reinterpret_cast<const uint4*>(Bptr + kb + 64)[i];
        }
#pragma unroll
        for (int ks = 0; ks < 2; ++ks) {
            f16x8 af[4], bf[4];
#pragma unroll
            for (int mi = 0; mi < 4; ++mi) {
                int r  = wm * 64 + mi * 16 + lc;
                int hw = (r * 64 + ks * 32 + g * 8) ^ ((r & 7) << 3);
                af[mi] = *reinterpret_cast<const f16x8*>(&As[hw]);
            }
#pragma unroll
            for (int ni = 0; ni < 4; ++ni) {
                int r  = wn * 64 + ni * 16 + lc;
                int hw = (r * 64 + ks * 32 + g * 8) ^ ((r & 7) << 3);
                bf[ni] = *reinterpret_cast<const f16x8*>(&Bs[hw]);
            }
#pragma unroll
            for (int mi = 0; mi < 4; ++mi)
#pragma unroll
                for (int ni = 0; ni < 4; ++ni)
                    acc[mi][ni] = __builtin_amdgcn_mfma_f32_16x16x32_f16(
                        af[mi], bf[ni], acc[mi][ni], 0, 0, 0);
        }
    }

    __syncthreads();

    float psum[4][4];
#pragma unroll
    for (int mi = 0; mi < 4; ++mi)
#pragma unroll
        for (int r = 0; r < 4; ++r) psum[mi][r] = 0.f;

#pragma unroll
    for (int mi = 0; mi < 4; ++mi) {
#pragma unroll
        for (int ni = 0; ni < 4; ++ni) {
            int n = n0 + wn * 64 + ni * 16 + lc;
            float vn = v[n];
            float bb = be[n] + bd[n];
#pragma unroll
            for (int r = 0; r < 4; ++r) {
                int b = mi * 16 + g * 4 + r;
                float x = acc[mi][ni][r] + decb[(size_t)b * ADIM + n] + bb;
                psum[mi][r] = fmaf(fast_tanh(x), vn, psum[mi][r]);
            }
        }
    }
#pragma unroll
    for (int mi = 0; mi < 4; ++mi)
#pragma unroll
        for (int r = 0; r < 4; ++r) {
            float s = psum[mi][r];
            s += __shfl_xor(s, 1);
            s += __shfl_xor(s, 2);
            s += __shfl_xor(s, 4);
            s += __shfl_xor(s, 8);
            psum[mi][r] = s;
        }

    float* red = reinterpret_cast<float*>(As);
    if (lc == 0) {
#pragma unroll
        for (int mi = 0; mi < 4; ++mi)
#pragma unroll
            for (int r = 0; r < 4; ++r) {
                int row = wm * 64 + mi * 16 + g * 4 + r;
                red[row * 2 + wn] = psum[mi][r];
            }
    }
    __syncthreads();
    if (tid < 128)
        atomicAdd(&scores[m0 + tid], red[tid * 2] + red[tid * 2 + 1]);
}

// ---------------------------------------------------------------------------
// Masked softmax over S per batch column, in place. One block per b.
// ---------------------------------------------------------------------------
__global__ __launch_bounds__(256)
void softmax_kernel(const int* __restrict__ lens, float* __restrict__ attn)
{
    const int b   = blockIdx.x;
    const int tid = threadIdx.x;
    const int len = lens[b];

    float sc[4];
#pragma unroll
    for (int k = 0; k < 4; ++k) {
        int s = k * 256 + tid;
        float x = attn[(size_t)s * BSZ + b];
        sc[k] = (s < len) ? x : NEG_MASK;
    }

    __shared__ float red[8];

    float m = fmaxf(fmaxf(sc[0], sc[1]), fmaxf(sc[2], sc[3]));
#pragma unroll
    for (int off = 32; off > 0; off >>= 1) m = fmaxf(m, __shfl_xor(m, off));
    if ((tid & 63) == 0) red[tid >> 6] = m;
    __syncthreads();
    m = fmaxf(fmaxf(red[0], red[1]), fmaxf(red[2], red[3]));

    float e[4];
    float sum = 0.f;
#pragma unroll
    for (int k = 0; k < 4; ++k) { e[k] = expf(sc[k] - m); sum += e[k]; }
#pragma unroll
    for (int off = 32; off > 0; off >>= 1) sum += __shfl_xor(sum, off);
    __syncthreads();
    if ((tid & 63) == 0) red[4 + (tid >> 6)] = sum;
    __syncthreads();
    float total = red[4] + red[5] + red[6] + red[7];
    float inv = 1.f / total;

#pragma unroll
    for (int k = 0; k < 4; ++k) {
        int s = k * 256 + tid;
        attn[(size_t)s * BSZ + b] = e[k] * inv;
    }
}

// ---------------------------------------------------------------------------
// ctx[b][c] = sum_s attn[s][b] * hids[s][b][c]   (fp32 source, coalesced)
// ---------------------------------------------------------------------------
__global__ __launch_bounds__(256)
void ctx_kernel(const float* __restrict__ hids, const float* __restrict__ attn,
                float* __restrict__ ctx)
{
    const int b   = blockIdx.x;
    const int s0  = blockIdx.y * (SRC_LEN / 8);
    const int tid = threadIdx.x;

    float4 acc = make_float4(0.f, 0.f, 0.f, 0.f);
    for (int s = s0; s < s0 + SRC_LEN / 8; ++s) {
        float w = attn[(size_t)s * BSZ + b];
        if (w != 0.f) {
            float4 h = *reinterpret_cast<const float4*>(
                &hids[((size_t)s * BSZ + b) * CDIM + tid * 4]);
            acc.x = fmaf(w, h.x, acc.x);
            acc.y = fmaf(w, h.y, acc.y);
            acc.z = fmaf(w, h.z, acc.z);
            acc.w = fmaf(w, h.w, acc.w);
        }
    }
    float* dst = &ctx[(size_t)b * CDIM + tid * 4];
    atomicAdd(dst + 0, acc.x);
    atomicAdd(dst + 1, acc.y);
    atomicAdd(dst + 2, acc.z);
    atomicAdd(dst + 3, acc.w);
}

// ---------------------------------------------------------------------------
extern "C" void kernel_launch(void* const* d_in, const int* in_sizes, int n_in,
                              void* d_out, int out_size, void* d_ws, size_t ws_size,
                              hipStream_t stream)
{
    const float* dsr   = (const float*)d_in[0];
    const float* hids  = (const float*)d_in[1];
    const int*   lens  = (const int*)  d_in[2];
    const float* W_enc = (const float*)d_in[3];
    const float* b_enc = (const float*)d_in[4];
    const float* W_dec = (const float*)d_in[5];
    const float* b_dec = (const float*)d_in[6];
    const float* v     = (const float*)d_in[7];

    float* out  = (float*)d_out;
    float* ctx  = out;                       // [64*1024]
    float* attn = out + BSZ * CDIM;          // [1024*64] scores -> probs

    const size_t decb_b = (size_t)BSZ * ADIM * 4;     // 256 KB
    const size_t wf16_b = (size_t)ADIM * KDIM * 2;    // 2 MB
    const size_t af16_b = (size_t)MROWS * KDIM * 2;   // 128 MB

    float*    decb = (float*)d_ws;
    _Float16* Wt   = (_Float16*)((char*)d_ws + decb_b);
    _Float16* At   = (_Float16*)((char*)d_ws + decb_b + wf16_b);

    const bool fast = ws_size >= decb_b + wf16_b + af16_b;

    hipMemsetAsync(d_out, 0, (size_t)(BSZ * CDIM + SRC_LEN * BSZ) * sizeof(float), stream);
    hipMemsetAsync(d_ws, 0, decb_b, stream);   // decb is an atomic target

    dec_kernel<<<dim3(16, 4), 256, 0, stream>>>(dsr, W_dec, decb);

    if (fast) {
        convert_tiled256_kernel<<<(ADIM / 256) * 16 * 8, 256, 0, stream>>>(W_enc, Wt);
        convert_tiled256_kernel<<<(MROWS / 256) * 16 * 8, 256, 0, stream>>>(hids, At);
        enc_score_256<<<1024, 512, 0, stream>>>(At, Wt, decb, b_enc, b_dec, v, attn);
    } else {
        convert8_kernel<<<ADIM * KDIM / 8 / 256, 256, 0, stream>>>(W_enc, Wt);
        enc_score_fallback<<<4096, 256, 0, stream>>>(hids, Wt, decb, b_enc, b_dec, v, attn);
    }
    softmax_kernel<<<BSZ, 256, 0, stream>>>(lens, attn);
    ctx_kernel<<<dim3(BSZ, 8), 256, 0, stream>>>(hids, attn, ctx);
}